// Round 1
// baseline (971.519 us; speedup 1.0000x reference)
//
#include <hip/hip_runtime.h>

typedef short short8 __attribute__((ext_vector_type(8)));
typedef float floatx4 __attribute__((ext_vector_type(4)));
typedef unsigned short ushort8v __attribute__((ext_vector_type(8)));

#define B_ 8
#define S_ 1024
#define H_ 1024
#define NH_ 16
#define HD_ 64

__device__ __forceinline__ unsigned short f2bf(float f) {
  unsigned u = __float_as_uint(f);
  u += 0x7fffu + ((u >> 16) & 1u);   // RNE to bf16
  return (unsigned short)(u >> 16);
}

__device__ __forceinline__ floatx4 mfma16(short8 a, short8 b, floatx4 c) {
  return __builtin_amdgcn_mfma_f32_16x16x32_bf16(a, b, c, 0, 0, 0);
}

// ---------------- convert fp32 -> bf16, optional perturbation w + g*relu(w) --
__global__ void __launch_bounds__(256) cvt_kernel(const float* __restrict__ src,
                                                  unsigned short* __restrict__ dst,
                                                  const float* __restrict__ gamma,
                                                  int n) {
  int i = (blockIdx.x * 256 + threadIdx.x) * 4;
  if (i >= n) return;
  float g = gamma ? gamma[0] : 0.0f;
  float4 v = *(const float4*)(src + i);
  ushort4 o;
  o.x = f2bf(v.x + g * fmaxf(v.x, 0.f));
  o.y = f2bf(v.y + g * fmaxf(v.y, 0.f));
  o.z = f2bf(v.z + g * fmaxf(v.z, 0.f));
  o.w = f2bf(v.w + g * fmaxf(v.w, 0.f));
  *(ushort4*)(dst + i) = o;
}

// ---------------- shared GEMM mainloop: C(128x128) = A[M,K] * B^T  (bf16) ----
// As/Bs: [128][32] bf16 tiles. 256 threads, 4 waves each computing 64x64.
__device__ __forceinline__ void gemm_mainloop(const unsigned short* __restrict__ Ag,
                                              const unsigned short* __restrict__ Bg,
                                              int K,
                                              unsigned short* As, unsigned short* Bs,
                                              floatx4 acc[4][4]) {
  const int tid = threadIdx.x;
  const int l = tid & 63, w = tid >> 6;
  const int l15 = l & 15, l4 = l >> 4;
  const int wm = (w & 1) << 6, wn = (w >> 1) << 6;
  const int r0 = tid >> 2;           // 0..63
  const int c0 = (tid & 3) << 3;     // 0,8,16,24 (elements)
  for (int k0 = 0; k0 < K; k0 += 32) {
    __syncthreads();
    *(uint4*)&As[r0 * 32 + c0]        = *(const uint4*)&Ag[(size_t)r0 * K + k0 + c0];
    *(uint4*)&As[(r0 + 64) * 32 + c0] = *(const uint4*)&Ag[(size_t)(r0 + 64) * K + k0 + c0];
    *(uint4*)&Bs[r0 * 32 + c0]        = *(const uint4*)&Bg[(size_t)r0 * K + k0 + c0];
    *(uint4*)&Bs[(r0 + 64) * 32 + c0] = *(const uint4*)&Bg[(size_t)(r0 + 64) * K + k0 + c0];
    __syncthreads();
    short8 a[4], bb[4];
#pragma unroll
    for (int i = 0; i < 4; ++i)
      a[i] = *(const short8*)&As[(wm + i * 16 + l15) * 32 + l4 * 8];
#pragma unroll
    for (int j = 0; j < 4; ++j)
      bb[j] = *(const short8*)&Bs[(wn + j * 16 + l15) * 32 + l4 * 8];
#pragma unroll
    for (int i = 0; i < 4; ++i)
#pragma unroll
      for (int j = 0; j < 4; ++j)
        acc[i][j] = mfma16(a[i], bb[j], acc[i][j]);
  }
}

// ---------------- QKV: q/k/v = x @ W^T + b, bf16 out [8192,1024] -------------
__global__ void __launch_bounds__(256) gemm_qkv(
    const unsigned short* __restrict__ xb,
    const unsigned short* __restrict__ wq, const unsigned short* __restrict__ wk,
    const unsigned short* __restrict__ wv,
    const float* __restrict__ bq, const float* __restrict__ bk, const float* __restrict__ bv,
    unsigned short* __restrict__ oq, unsigned short* __restrict__ ok,
    unsigned short* __restrict__ ov) {
  __shared__ unsigned short As[128 * 32];
  __shared__ unsigned short Bs[128 * 32];
  const int z = blockIdx.z;
  const unsigned short* W = (z == 0) ? wq : (z == 1) ? wk : wv;
  const float* bias        = (z == 0) ? bq : (z == 1) ? bk : bv;
  unsigned short* O        = (z == 0) ? oq : (z == 1) ? ok : ov;
  const int nBase = blockIdx.x * 128, mBase = blockIdx.y * 128;
  floatx4 acc[4][4];
  const floatx4 fz = {0.f, 0.f, 0.f, 0.f};
#pragma unroll
  for (int i = 0; i < 4; ++i)
#pragma unroll
    for (int j = 0; j < 4; ++j) acc[i][j] = fz;
  gemm_mainloop(xb + (size_t)mBase * H_, W + (size_t)nBase * H_, H_, As, Bs, acc);
  const int l = threadIdx.x & 63, w = threadIdx.x >> 6;
  const int l15 = l & 15, l4 = l >> 4;
  const int wm = (w & 1) << 6, wn = (w >> 1) << 6;
#pragma unroll
  for (int i = 0; i < 4; ++i) {
    int row = mBase + wm + i * 16 + l4 * 4;
#pragma unroll
    for (int j = 0; j < 4; ++j) {
      int col = nBase + wn + j * 16 + l15;
      float bcol = bias[col];
#pragma unroll
      for (int r = 0; r < 4; ++r)
        O[(size_t)(row + r) * H_ + col] = f2bf(acc[i][j][r] + bcol);
    }
  }
}

// ---------------- V transpose: [B*S, NH*HD] -> [B,NH,HD,S] -------------------
__global__ void __launch_bounds__(256) transpose_v(const unsigned short* __restrict__ vb,
                                                   unsigned short* __restrict__ vt) {
  const int st = blockIdx.x, h = blockIdx.y, b = blockIdx.z;
  __shared__ unsigned short t[64 * 72];  // pad 8 -> 144B rows (16B aligned)
  const int tid = threadIdx.x;
  const unsigned short* src = vb + (size_t)(b * S_ + st * 64) * H_ + h * HD_;
  for (int c = tid; c < 512; c += 256) {
    int i = c >> 3, dg = (c & 7) << 3;
    *(uint4*)&t[i * 72 + dg] = *(const uint4*)&src[(size_t)i * H_ + dg];
  }
  __syncthreads();
  unsigned short* dst = vt + ((size_t)(b * NH_ + h) * HD_) * S_ + st * 64;
  for (int c = tid; c < 512; c += 256) {
    int d = c >> 3, ig = (c & 7) << 3;
    ushort8v v;
#pragma unroll
    for (int ii = 0; ii < 8; ++ii) v[ii] = t[(ig + ii) * 72 + d];
    *(ushort8v*)&dst[(size_t)d * S_ + ig] = v;
  }
}

// ---------------- attention: probs (fp32) + ctx (bf16) ----------------------
// block = (qt, h, b): 64 q-rows. 4 waves x 16 rows. BK=128.
__global__ void __launch_bounds__(256) attn_kernel(
    const unsigned short* __restrict__ qg_, const unsigned short* __restrict__ kg_,
    const unsigned short* __restrict__ vtg_,
    float* __restrict__ probs, unsigned short* __restrict__ ctxb) {
  const int qt = blockIdx.x, h = blockIdx.y, b = blockIdx.z;
  __shared__ unsigned short Qs[64 * 64];
  __shared__ unsigned short Ks[128 * 64];
  __shared__ unsigned short Vts[64 * 128];
  __shared__ unsigned short Ps[64 * 128];
  const int tid = threadIdx.x;
  const int l = tid & 63, w = tid >> 6;
  const int l15 = l & 15, l4 = l >> 4;

  const unsigned short* qg = qg_ + ((size_t)(b * S_) + qt * 64) * H_ + h * HD_;
  const unsigned short* kg = kg_ + (size_t)(b * S_) * H_ + h * HD_;
  const unsigned short* vg = vtg_ + ((size_t)(b * NH_ + h) * HD_) * S_;

  for (int c = tid; c < 512; c += 256) {  // stage Q 64x64
    int row = c >> 3, cg = (c & 7) << 3;
    *(uint4*)&Qs[row * 64 + cg] = *(const uint4*)&qg[(size_t)row * H_ + cg];
  }
  __syncthreads();
  short8 aq0 = *(const short8*)&Qs[(w * 16 + l15) * 64 + l4 * 8];
  short8 aq1 = *(const short8*)&Qs[(w * 16 + l15) * 64 + 32 + l4 * 8];

  // -------- pass 1: row sums of exp(scores); no max-sub (|s| <~ 25) --------
  float esum[4] = {0.f, 0.f, 0.f, 0.f};
  for (int kt = 0; kt < 8; ++kt) {
    __syncthreads();
    for (int c = tid; c < 1024; c += 256) {
      int row = c >> 3, cg = (c & 7) << 3;
      *(uint4*)&Ks[row * 64 + cg] = *(const uint4*)&kg[(size_t)(kt * 128 + row) * H_ + cg];
    }
    __syncthreads();
#pragma unroll
    for (int j = 0; j < 8; ++j) {
      short8 b0 = *(const short8*)&Ks[(j * 16 + l15) * 64 + l4 * 8];
      short8 b1 = *(const short8*)&Ks[(j * 16 + l15) * 64 + 32 + l4 * 8];
      floatx4 s = {0.f, 0.f, 0.f, 0.f};
      s = mfma16(aq0, b0, s);
      s = mfma16(aq1, b1, s);
#pragma unroll
      for (int r = 0; r < 4; ++r) esum[r] += __expf(s[r]);
    }
  }
#pragma unroll
  for (int m = 1; m < 16; m <<= 1)
#pragma unroll
    for (int r = 0; r < 4; ++r) esum[r] += __shfl_xor(esum[r], m, 64);
  float rinv[4];
#pragma unroll
  for (int r = 0; r < 4; ++r) rinv[r] = 1.0f / esum[r];

  // -------- pass 2: probs write + PV accumulate ----------------------------
  const floatx4 fz = {0.f, 0.f, 0.f, 0.f};
  floatx4 cacc[4];
#pragma unroll
  for (int dt = 0; dt < 4; ++dt) cacc[dt] = fz;
  const int qrow_base = qt * 64 + w * 16 + l4 * 4;
  for (int kt = 0; kt < 8; ++kt) {
    __syncthreads();
    for (int c = tid; c < 1024; c += 256) {
      int row = c >> 3, cg = (c & 7) << 3;
      *(uint4*)&Ks[row * 64 + cg] = *(const uint4*)&kg[(size_t)(kt * 128 + row) * H_ + cg];
    }
    for (int c = tid; c < 1024; c += 256) {
      int row = c >> 4, cg = (c & 15) << 3;
      *(uint4*)&Vts[row * 128 + cg] = *(const uint4*)&vg[(size_t)row * S_ + kt * 128 + cg];
    }
    __syncthreads();
#pragma unroll
    for (int j = 0; j < 8; ++j) {
      short8 b0 = *(const short8*)&Ks[(j * 16 + l15) * 64 + l4 * 8];
      short8 b1 = *(const short8*)&Ks[(j * 16 + l15) * 64 + 32 + l4 * 8];
      floatx4 s = {0.f, 0.f, 0.f, 0.f};
      s = mfma16(aq0, b0, s);
      s = mfma16(aq1, b1, s);
      float* pp = probs + ((size_t)((b * NH_ + h) * S_) + qrow_base) * S_ + kt * 128 + j * 16 + l15;
#pragma unroll
      for (int r = 0; r < 4; ++r) {
        float p = __expf(s[r]) * rinv[r];
        pp[(size_t)r * S_] = p;
        Ps[(w * 16 + l4 * 4 + r) * 128 + j * 16 + l15] = f2bf(p);
      }
    }
    __syncthreads();
    short8 ap[4];
#pragma unroll
    for (int ks = 0; ks < 4; ++ks)
      ap[ks] = *(const short8*)&Ps[(w * 16 + l15) * 128 + ks * 32 + l4 * 8];
#pragma unroll
    for (int dt = 0; dt < 4; ++dt)
#pragma unroll
      for (int ks = 0; ks < 4; ++ks) {
        short8 bv = *(const short8*)&Vts[(dt * 16 + l15) * 128 + ks * 32 + l4 * 8];
        cacc[dt] = mfma16(ap[ks], bv, cacc[dt]);
      }
  }
  const int rowg = b * S_ + qt * 64 + w * 16 + l4 * 4;
#pragma unroll
  for (int dt = 0; dt < 4; ++dt)
#pragma unroll
    for (int r = 0; r < 4; ++r)
      ctxb[(size_t)(rowg + r) * H_ + h * HD_ + dt * 16 + l15] = f2bf(cacc[dt][r]);
}

// ---------------- out-proj: h = ctx @ p(Wo)^T + p(bo) + x (fp32) ------------
__global__ void __launch_bounds__(256) gemm_out(
    const unsigned short* __restrict__ ctxb, const unsigned short* __restrict__ wob,
    const float* __restrict__ bo, const float* __restrict__ gln,
    const float* __restrict__ xres, float* __restrict__ hres) {
  __shared__ unsigned short As[128 * 32];
  __shared__ unsigned short Bs[128 * 32];
  const int nBase = blockIdx.x * 128, mBase = blockIdx.y * 128;
  floatx4 acc[4][4];
  const floatx4 fz = {0.f, 0.f, 0.f, 0.f};
#pragma unroll
  for (int i = 0; i < 4; ++i)
#pragma unroll
    for (int j = 0; j < 4; ++j) acc[i][j] = fz;
  gemm_mainloop(ctxb + (size_t)mBase * H_, wob + (size_t)nBase * H_, H_, As, Bs, acc);
  const float g = gln[0];
  const int l = threadIdx.x & 63, w = threadIdx.x >> 6;
  const int l15 = l & 15, l4 = l >> 4;
  const int wm = (w & 1) << 6, wn = (w >> 1) << 6;
#pragma unroll
  for (int i = 0; i < 4; ++i) {
    int row = mBase + wm + i * 16 + l4 * 4;
#pragma unroll
    for (int j = 0; j < 4; ++j) {
      int col = nBase + wn + j * 16 + l15;
      float pb = bo[col];
      pb += g * fmaxf(pb, 0.f);
#pragma unroll
      for (int r = 0; r < 4; ++r)
        hres[(size_t)(row + r) * H_ + col] =
            acc[i][j][r] + pb + xres[(size_t)(row + r) * H_ + col];
    }
  }
}

// ---------------- LayerNorm (no weight/bias), biased var, eps=1e-12 ---------
__global__ void __launch_bounds__(256) ln_kernel(const float* __restrict__ hres,
                                                 float* __restrict__ out) {
  const int row = blockIdx.x;
  const int tid = threadIdx.x;
  const float* xr = hres + (size_t)row * H_;
  float4 v = *(const float4*)&xr[tid * 4];
  float s = v.x + v.y + v.z + v.w;
  float q = v.x * v.x + v.y * v.y + v.z * v.z + v.w * v.w;
#pragma unroll
  for (int m = 1; m < 64; m <<= 1) {
    s += __shfl_xor(s, m, 64);
    q += __shfl_xor(q, m, 64);
  }
  __shared__ float sh[8];
  const int w = tid >> 6, l = tid & 63;
  if (l == 0) { sh[w] = s; sh[4 + w] = q; }
  __syncthreads();
  s = sh[0] + sh[1] + sh[2] + sh[3];
  q = sh[4] + sh[5] + sh[6] + sh[7];
  float mean = s * (1.f / 1024.f);
  float var = q * (1.f / 1024.f) - mean * mean;
  float inv = rsqrtf(var + 1e-12f);
  float4 o;
  o.x = (v.x - mean) * inv;
  o.y = (v.y - mean) * inv;
  o.z = (v.z - mean) * inv;
  o.w = (v.w - mean) * inv;
  *(float4*)&out[(size_t)row * H_ + tid * 4] = o;
}

extern "C" void kernel_launch(void* const* d_in, const int* in_sizes, int n_in,
                              void* d_out, int out_size, void* d_ws, size_t ws_size,
                              hipStream_t stream) {
  const float* x   = (const float*)d_in[0];
  const float* Wq  = (const float*)d_in[1];
  const float* bq  = (const float*)d_in[2];
  const float* Wk  = (const float*)d_in[3];
  const float* bk  = (const float*)d_in[4];
  const float* Wv  = (const float*)d_in[5];
  const float* bv  = (const float*)d_in[6];
  const float* Wo  = (const float*)d_in[7];
  const float* bo  = (const float*)d_in[8];
  const float* gLN = (const float*)d_in[10];

  float* out   = (float*)d_out;
  float* probs = out + (size_t)B_ * S_ * H_;  // 8388608 floats of LN output first

  // workspace layout (bf16 elements); ctx aliases xb, hres aliases qb+kb
  unsigned short* xb  = (unsigned short*)d_ws;
  unsigned short* wqb = xb + 8388608;
  unsigned short* wkb = wqb + 1048576;
  unsigned short* wvb = wkb + 1048576;
  unsigned short* wob = wvb + 1048576;
  unsigned short* qb  = wob + 1048576;
  unsigned short* kb  = qb + 8388608;
  unsigned short* vb  = kb + 8388608;
  unsigned short* vt  = vb + 8388608;
  unsigned short* ctxb = xb;        // xb dead after gemm_qkv
  float* hres = (float*)qb;         // qb/kb dead after attn

  cvt_kernel<<<8192, 256, 0, stream>>>(x, xb, nullptr, 8388608);
  cvt_kernel<<<1024, 256, 0, stream>>>(Wq, wqb, nullptr, 1048576);
  cvt_kernel<<<1024, 256, 0, stream>>>(Wk, wkb, nullptr, 1048576);
  cvt_kernel<<<1024, 256, 0, stream>>>(Wv, wvb, nullptr, 1048576);
  cvt_kernel<<<1024, 256, 0, stream>>>(Wo, wob, gLN, 1048576);

  gemm_qkv<<<dim3(8, 64, 3), 256, 0, stream>>>(xb, wqb, wkb, wvb, bq, bk, bv, qb, kb, vb);
  transpose_v<<<dim3(16, 16, 8), 256, 0, stream>>>(vb, vt);
  attn_kernel<<<dim3(16, 16, 8), 256, 0, stream>>>(qb, kb, vt, probs, ctxb);
  gemm_out<<<dim3(8, 64, 1), 256, 0, stream>>>(ctxb, wob, bo, gLN, x, hres);
  ln_kernel<<<8192, 256, 0, stream>>>(hres, out);
}